// Round 14
// baseline (557.389 us; speedup 1.0000x reference)
//
#include <hip/hip_runtime.h>
#include <hip/hip_bf16.h>
#include <math.h>

typedef __hip_bfloat16 bf16;
typedef __attribute__((ext_vector_type(4))) float f32x4;
typedef __attribute__((ext_vector_type(8))) __bf16 bf16x8;

static constexpr int HID    = 2560;
static constexpr int LRUD   = 2560;
static constexpr int HEADSN = 10;
static constexpr int BWID   = 256;          // LRU / HEADS
static constexpr int SEQL   = 4096;
static constexpr int BATCHN = 2;
static constexpr int NTOK   = BATCHN * SEQL;   // 8192
static constexpr int NCHUNK = 128;             // scan chunks per sequence
static constexpr int CHLEN  = 32;              // NCHUNK*CHLEN == SEQL

#define GAS __attribute__((address_space(1)))
#define LAS __attribute__((address_space(3)))
#define MEMFENCE asm volatile("" ::: "memory")
#define PHASE_SYNC                                        \
  __builtin_amdgcn_s_barrier(); MEMFENCE;                 \
  asm volatile("s_waitcnt lgkmcnt(0)" ::: "memory");
#define PHASE_END                                         \
  __builtin_amdgcn_s_barrier(); MEMFENCE;
#define VMGATE6 asm volatile("s_waitcnt vmcnt(6)" ::: "memory")
#define VMGATE0 asm volatile("s_waitcnt vmcnt(0)" ::: "memory")
#define LGKM8   asm volatile("s_waitcnt lgkmcnt(8)" ::: "memory")

__device__ __forceinline__ void async_copy16(void* lds, const void* g) {
  __builtin_amdgcn_global_load_lds((const GAS unsigned int*)g,
                                   (LAS unsigned int*)lds, 16, 0, 0);
}

// ---------------------------------------------------------------------------
// R12-proven 256^2 quadrant 8-phase dual GEMM (measured 249us, MfmaUtil 37%,
// FETCH 246MB — best dual variant across R4..R13). 8 waves (2M x 4N),
// per-wave 128x64: acc[8][4] (128 AGPR); a[4][2]+bl[2][2]+bh[2][2] (64 VGPR).
// Per phase: ONE C-quadrant x K=64 (16 MFMA) + ONE half-tile staged.
// Gate ledger and write-after-read hazards as documented in R12.
// EPI 1: dual bf16 (z: 0=gelu->out0, 1=linear->out1).
// ---------------------------------------------------------------------------
template<int EPI>
__global__ __launch_bounds__(512, 2)
void gemm256_kernel(const bf16* __restrict__ A, int lda,
                    const bf16* __restrict__ B0p, const bf16* __restrict__ B1p,
                    int ldb,
                    const float* __restrict__ bias0, const float* __restrict__ bias1,
                    void* __restrict__ out0, void* __restrict__ out1,
                    int ldc, int K)
{
  __shared__ __align__(16) bf16 As[2][256 * 64];
  __shared__ __align__(16) bf16 Bs[2][256 * 64];

  const int tid  = threadIdx.x;
  const int wave = tid >> 6;
  const int lane = tid & 63;
  const int wm   = wave >> 2;     // 0..1
  const int wn   = wave & 3;      // 0..3

  // bijective XCD swizzle (nxy % 8 == 0)
  const int nxy  = gridDim.x * gridDim.y;
  const int orig = blockIdx.y * gridDim.x + blockIdx.x;
  const int swz  = (orig & 7) * (nxy >> 3) + (orig >> 3);
  const int m0   = (swz / gridDim.x) * 256;
  const int n0   = (swz % gridDim.x) * 256;

  const int zsel = (EPI == 1) ? (int)blockIdx.z : 0;
  const bf16*  Bw   = zsel ? B1p : B0p;
  const float* bias = zsel ? bias1 : bias0;

  const int NT = K / 64;
  f32x4  acc[8][4] = {};
  bf16x8 a[4][2], bl[2][2], bh[2][2];

  const int srow = tid >> 3;           // 0..63 within a chunk
  const int spb  = (tid & 7) * 16;     // physical byte col
  const int scb  = spb ^ ((srow & 7) << 4);   // stage source col (thread-const)

  // hoisted fragment addressing (row&7 == lane&7 for all frag rows)
  const int lrow = lane & 15;
  const int swzc = (lane & 7) << 4;
  const int col0 = ((lane >> 4) * 16) ^ swzc;         // ks=0
  const int col1 = (64 + (lane >> 4) * 16) ^ swzc;    // ks=1
  const char* aBase = (const char*)&As[0][0] + (wm * 128 + lrow) * 128;
  const char* bBase = (const char*)&Bs[0][0] + (wn * 64 + lrow) * 128;
  constexpr int BUFB = 256 * 64 * 2;   // bytes per LDS buffer

  auto stageA = [&](int t, int c) {    // chunk c: tile rows c*64..c*64+63
    const int r = c * 64 + srow;
    async_copy16(&As[t & 1][c * 4096 + wave * 512],
                 A + (size_t)(m0 + r) * lda + t * 64 + (scb >> 1));
  };
  auto stageB = [&](int t, int c) {
    const int r = c * 64 + srow;
    async_copy16(&Bs[t & 1][c * 4096 + wave * 512],
                 Bw + (size_t)(n0 + r) * ldb + t * 64 + (scb >> 1));
  };
  auto stA_lo = [&](int t) { stageA(t, 0); stageA(t, 2); };  // a-lo rows of both wm
  auto stA_hi = [&](int t) { stageA(t, 1); stageA(t, 3); };
  auto stB01  = [&](int t) { stageB(t, 0); stageB(t, 1); };
  auto stB23  = [&](int t) { stageB(t, 2); stageB(t, 3); };

  auto readAhalf = [&](int buf, int half) {    // 8 ds_read_b128 -> a[4][2]
    const char* p = aBase + buf * BUFB + half * 4 * 2048;
#pragma unroll
    for (int j = 0; j < 4; ++j) {
      a[j][0] = *(const bf16x8*)(p + j * 2048 + col0);
      a[j][1] = *(const bf16x8*)(p + j * 2048 + col1);
    }
  };
  auto readBlo = [&](int buf) {                // 4 reads -> bl[2][2] (fn 0,1)
    const char* p = bBase + buf * BUFB;
#pragma unroll
    for (int f = 0; f < 2; ++f) {
      bl[f][0] = *(const bf16x8*)(p + f * 2048 + col0);
      bl[f][1] = *(const bf16x8*)(p + f * 2048 + col1);
    }
  };
  auto readBhi = [&](int buf) {                // 4 reads -> bh[2][2] (fn 2,3)
    const char* p = bBase + buf * BUFB + 2 * 2048;
#pragma unroll
    for (int f = 0; f < 2; ++f) {
      bh[f][0] = *(const bf16x8*)(p + f * 2048 + col0);
      bh[f][1] = *(const bf16x8*)(p + f * 2048 + col1);
    }
  };
  auto mfmaQ = [&](int fmB, int fnB, bf16x8 (&bx)[2][2]) {  // 16 MFMA
#pragma unroll
    for (int ks = 0; ks < 2; ++ks)
#pragma unroll
      for (int fn = 0; fn < 2; ++fn)
#pragma unroll
        for (int fm = 0; fm < 4; ++fm)
          acc[fmB + fm][fnB + fn] = __builtin_amdgcn_mfma_f32_16x16x32_bf16(
              a[fm][ks], bx[fn][ks], acc[fmB + fm][fnB + fn], 0, 0, 0);
  };

  // prologue: t0 all 4 half-tiles + t1's {Alo,B01,B23} = 14 calls; drain t0
  stA_lo(0); stB01(0); stB23(0); stA_hi(0);
  stA_lo(1); stB01(1); stB23(1);
  VMGATE6;
  PHASE_END;

  const int NI = NT / 2;
  for (int i = 0; i < NI; ++i) {
    const int  t0 = 2 * i, t1 = 2 * i + 1;
    const bool s2 = (t0 + 2) < NT;       // == (t1+2)<NT since NT even

    // P1: Q1 on buf0
    readAhalf(0, 0); readBlo(0);
    stA_hi(t1);
    LGKM8;
    PHASE_SYNC;
    __builtin_amdgcn_s_setprio(1); mfmaQ(0, 0, bl); __builtin_amdgcn_s_setprio(0);
    PHASE_END;
    // P2: Q2
    readBhi(0);
    if (s2) stA_lo(t0 + 2);
    PHASE_SYNC;
    __builtin_amdgcn_s_setprio(1); mfmaQ(0, 2, bh); __builtin_amdgcn_s_setprio(0);
    PHASE_END;
    // P3: Q3 (a <- a-hi)
    readAhalf(0, 1);
    if (s2) stB01(t0 + 2);
    PHASE_SYNC;
    __builtin_amdgcn_s_setprio(1); mfmaQ(4, 2, bh); __builtin_amdgcn_s_setprio(0);
    PHASE_END;
    // P4: Q4 (reuse a-hi + bl); GATE: all of t1 landed
    if (s2) stB23(t0 + 2);
    PHASE_SYNC;
    __builtin_amdgcn_s_setprio(1); mfmaQ(4, 0, bl); __builtin_amdgcn_s_setprio(0);
    if (s2) { VMGATE6; } else { VMGATE0; }
    PHASE_END;
    // P5: Q1 on buf1
    readAhalf(1, 0); readBlo(1);
    if (s2) stA_hi(t0 + 2);
    LGKM8;
    PHASE_SYNC;
    __builtin_amdgcn_s_setprio(1); mfmaQ(0, 0, bl); __builtin_amdgcn_s_setprio(0);
    PHASE_END;
    // P6: Q2
    readBhi(1);
    if (s2) stA_lo(t1 + 2);
    PHASE_SYNC;
    __builtin_amdgcn_s_setprio(1); mfmaQ(0, 2, bh); __builtin_amdgcn_s_setprio(0);
    PHASE_END;
    // P7: Q3
    readAhalf(1, 1);
    if (s2) stB01(t1 + 2);
    PHASE_SYNC;
    __builtin_amdgcn_s_setprio(1); mfmaQ(4, 2, bh); __builtin_amdgcn_s_setprio(0);
    PHASE_END;
    // P8: Q4; GATE: all of t0+2 landed
    if (s2) stB23(t1 + 2);
    PHASE_SYNC;
    __builtin_amdgcn_s_setprio(1); mfmaQ(4, 0, bl); __builtin_amdgcn_s_setprio(0);
    if (s2) { VMGATE6; }
    PHASE_END;
  }

  // epilogue: C/D layout: col = lane&15, row = (lane>>4)*4 + reg
  const int mrb = (lane >> 4) * 4;
  const int ncc = lane & 15;
#pragma unroll
  for (int fm = 0; fm < 8; ++fm) {
#pragma unroll
    for (int fn = 0; fn < 4; ++fn) {
      const int n  = n0 + wn * 64 + fn * 16 + ncc;
      const float bv = bias[n];
#pragma unroll
      for (int r = 0; r < 4; ++r) {
        const int m = m0 + wm * 128 + fm * 16 + mrb + r;
        const size_t idx = (size_t)m * ldc + n;
        float v = acc[fm][fn][r] + bv;
        if constexpr (EPI == 0) {
          ((float*)out0)[idx] = v;
        } else {
          if (zsel == 0) {
            const float t = tanhf(0.7978845608028654f * (v + 0.044715f * v * v * v));
            ((bf16*)out0)[idx] = __float2bfloat16(0.5f * v * (1.0f + t));
          } else {
            ((bf16*)out1)[idx] = __float2bfloat16(v);
          }
        }
      }
    }
  }
}

// ---------------------------------------------------------------------------
// R13-proven 128^2-tile quadrant 8-phase GEMM at 2 BLOCKS/CU — GEMM3 only
// (measured best GEMM3 variant: ~133us vs m97's ~150us). 4 waves (2M x 2N),
// per-wave 64x64: acc[4][4] (64 AGPR), frags ~48 VGPR, 64KB LDS.
// Gate ledger as documented in R13. EPI 0: fp32+bias out.
// ---------------------------------------------------------------------------
template<int EPI>
__global__ __launch_bounds__(256, 2)
void gemm128q_kernel(const bf16* __restrict__ A, int lda,
                     const bf16* __restrict__ B0p, const bf16* __restrict__ B1p,
                     int ldb,
                     const float* __restrict__ bias0, const float* __restrict__ bias1,
                     void* __restrict__ out0, void* __restrict__ out1,
                     int ldc, int K)
{
  __shared__ __align__(16) bf16 As[2][128 * 64];
  __shared__ __align__(16) bf16 Bs[2][128 * 64];

  const int tid  = threadIdx.x;
  const int wave = tid >> 6;      // 0..3
  const int lane = tid & 63;
  const int wm   = wave >> 1;     // 0..1
  const int wn   = wave & 1;      // 0..1

  // bijective XCD swizzle (nxy % 8 == 0)
  const int nxy  = gridDim.x * gridDim.y;
  const int orig = blockIdx.y * gridDim.x + blockIdx.x;
  const int swz  = (orig & 7) * (nxy >> 3) + (orig >> 3);
  const int m0   = (swz / gridDim.x) * 128;
  const int n0   = (swz % gridDim.x) * 128;

  const int zsel = (EPI == 1) ? (int)blockIdx.z : 0;
  const bf16*  Bw   = zsel ? B1p : B0p;
  const float* bias = zsel ? bias1 : bias0;

  const int NT = K / 64;
  f32x4  acc[4][4] = {};
  bf16x8 a[2][2], bl[2][2], bh[2][2];

  const int srow = tid >> 3;           // 0..31 within a 32-row chunk
  const int spb  = (tid & 7) * 16;
  const int scb  = spb ^ ((srow & 7) << 4);   // inverse-swizzled source col

  // hoisted fragment addressing (frag row&7 == lane&7)
  const int lrow = lane & 15;
  const int swzc = (lane & 7) << 4;
  const int col0 = ((lane >> 4) * 16) ^ swzc;         // ks=0
  const int col1 = (64 + (lane >> 4) * 16) ^ swzc;    // ks=1
  const char* aBase = (const char*)&As[0][0] + (wm * 64 + lrow) * 128;
  const char* bBase = (const char*)&Bs[0][0] + (wn * 64 + lrow) * 128;
  constexpr int BUFB = 128 * 64 * 2;   // bytes per LDS buffer

  auto stageA = [&](int t, int c) {    // chunk c: tile rows c*32..c*32+31
    const int r = c * 32 + srow;
    async_copy16(&As[t & 1][c * 2048 + wave * 512],
                 A + (size_t)(m0 + r) * lda + t * 64 + (scb >> 1));
  };
  auto stageB = [&](int t, int c) {
    const int r = c * 32 + srow;
    async_copy16(&Bs[t & 1][c * 2048 + wave * 512],
                 Bw + (size_t)(n0 + r) * ldb + t * 64 + (scb >> 1));
  };
  auto stA_lo = [&](int t) { stageA(t, 0); stageA(t, 2); };
  auto stA_hi = [&](int t) { stageA(t, 1); stageA(t, 3); };
  auto stB_lo = [&](int t) { stageB(t, 0); stageB(t, 2); };
  auto stB_hi = [&](int t) { stageB(t, 1); stageB(t, 3); };

  auto readAhalf = [&](int buf, int half) {    // 4 ds_read_b128 -> a[2][2]
    const char* p = aBase + buf * BUFB + half * 2 * 2048;
#pragma unroll
    for (int j = 0; j < 2; ++j) {
      a[j][0] = *(const bf16x8*)(p + j * 2048 + col0);
      a[j][1] = *(const bf16x8*)(p + j * 2048 + col1);
    }
  };
  auto readBlo = [&](int buf) {                // 4 reads -> bl (fn 0,1)
    const char* p = bBase + buf * BUFB;
#pragma unroll
    for (int f = 0; f < 2; ++f) {
      bl[f][0] = *(const bf16x8*)(p + f * 2048 + col0);
      bl[f][1] = *(const bf16x8*)(p + f * 2048 + col1);
    }
  };
  auto readBhi = [&](int buf) {                // 4 reads -> bh (fn 2,3)
    const char* p = bBase + buf * BUFB + 2 * 2048;
#pragma unroll
    for (int f = 0; f < 2; ++f) {
      bh[f][0] = *(const bf16x8*)(p + f * 2048 + col0);
      bh[f][1] = *(const bf16x8*)(p + f * 2048 + col1);
    }
  };
  auto mfmaQ = [&](int fmB, int fnB, bf16x8 (&bx)[2][2]) {  // 8 MFMA
#pragma unroll
    for (int ks = 0; ks < 2; ++ks)
#pragma unroll
      for (int fn = 0; fn < 2; ++fn)
#pragma unroll
        for (int fm = 0; fm < 2; ++fm)
          acc[fmB + fm][fnB + fn] = __builtin_amdgcn_mfma_f32_16x16x32_bf16(
              a[fm][ks], bx[fn][ks], acc[fmB + fm][fnB + fn], 0, 0, 0);
  };

  // prologue: t0 all 4 halves + t1 {Alo,Blo,Bhi} = 14 calls; drain t0
  stA_lo(0); stB_lo(0); stB_hi(0); stA_hi(0);
  stA_lo(1); stB_lo(1); stB_hi(1);
  VMGATE6;
  PHASE_END;

  const int NI = NT / 2;
  for (int i = 0; i < NI; ++i) {
    const int  t0 = 2 * i, t1 = 2 * i + 1;
    const bool s2 = (t0 + 2) < NT;       // == (t1+2)<NT since NT even

    // P1
    readAhalf(0, 0); readBlo(0);
    stA_hi(t1);
    PHASE_SYNC;
    __builtin_amdgcn_s_setprio(1); mfmaQ(0, 0, bl); __builtin_amdgcn_s_setprio(0);
    PHASE_END;
    // P2
    readBhi(0);
    if (s2) stA_lo(t0 + 2);
    PHASE_SYNC;
    __builtin_amdgcn_s_setprio(1); mfmaQ(0, 2, bh); __builtin_amdgcn_s_setprio(0);
    PHASE_END;
    // P3
    readAhalf(0, 1);
    if (s2) stB_lo(t0 + 2);
    PHASE_SYNC;
    __builtin_amdgcn_s_setprio(1); mfmaQ(2, 2, bh); __builtin_amdgcn_s_setprio(0);
    PHASE_END;
    // P4 (gate: t1 fully landed)
    if (s2) stB_hi(t0 + 2);
    PHASE_SYNC;
    __builtin_amdgcn_s_setprio(1); mfmaQ(2, 0, bl); __builtin_amdgcn_s_setprio(0);
    if (s2) { VMGATE6; } else { VMGATE0; }
    PHASE_END;
    // P5
    readAhalf(1, 0); readBlo(1);
    if (s2) stA_hi(t0 + 2);
    PHASE_SYNC;
    __builtin_amdgcn_s_setprio(1); mfmaQ(0, 0, bl); __builtin_amdgcn_s_setprio(0);
    PHASE_END;
    // P6
    readBhi(1);
    if (s2) stA_lo(t1 + 2);
    PHASE_SYNC;
    __builtin_amdgcn_s_setprio(1); mfmaQ(0, 2, bh); __builtin_amdgcn_s_setprio(0);
    PHASE_END;
    // P7
    readAhalf(1, 1);
    if (s2) stB_lo(t1 + 2);
    PHASE_SYNC;
    __builtin_amdgcn_s_setprio(1); mfmaQ(2, 2, bh); __builtin_amdgcn_s_setprio(0);
    PHASE_END;
    // P8 (gate: t0+2 fully landed)
    if (s2) stB_hi(t1 + 2);
    PHASE_SYNC;
    __builtin_amdgcn_s_setprio(1); mfmaQ(2, 0, bl); __builtin_amdgcn_s_setprio(0);
    if (s2) { VMGATE6; }
    PHASE_END;
  }

  // epilogue: C/D layout: col = lane&15, row = (lane>>4)*4 + reg
  const int mrb = (lane >> 4) * 4;
  const int ncc = lane & 15;
#pragma unroll
  for (int fm = 0; fm < 4; ++fm) {
#pragma unroll
    for (int fn = 0; fn < 4; ++fn) {
      const int n  = n0 + wn * 64 + fn * 16 + ncc;
      const float bv = bias[n];
#pragma unroll
      for (int r = 0; r < 4; ++r) {
        const int m = m0 + wm * 64 + fm * 16 + mrb + r;
        const size_t idx = (size_t)m * ldc + n;
        float v = acc[fm][fn][r] + bv;
        if constexpr (EPI == 0) {
          ((float*)out0)[idx] = v;
        } else {
          if (zsel == 0) {
            const float t = tanhf(0.7978845608028654f * (v + 0.044715f * v * v * v));
            ((bf16*)out0)[idx] = __float2bfloat16(0.5f * v * (1.0f + t));
          } else {
            ((bf16*)out1)[idx] = __float2bfloat16(v);
          }
        }
      }
    }
  }
}

// ---------------------------------------------------------------------------
// 128x128 m97-structure GEMM for BOTH block-diagonal gates + hoist.
// grid (2, 64, 20): z%10 = head, z/10 = {0:input gate, 1:a gate}; sigmoid epi.
// ---------------------------------------------------------------------------
__global__ __launch_bounds__(256)
void gate_gemm_kernel(const bf16* __restrict__ Conv,
                      const bf16* __restrict__ IGb, const bf16* __restrict__ AGb,
                      const float* __restrict__ ig_b, const float* __restrict__ ag_b,
                      bf16* __restrict__ Gx, bf16* __restrict__ Ga)
{
  __shared__ __align__(16) bf16 As[128 * 64];
  __shared__ __align__(16) bf16 Bs[128 * 64];

  const int tid  = threadIdx.x;
  const int wave = tid >> 6;
  const int lane = tid & 63;
  const int wy   = wave >> 1;
  const int wx   = wave & 1;
  const int m0   = blockIdx.y * 128;
  const int n0   = blockIdx.x * 128;
  const int head = blockIdx.z % HEADSN;
  const int sel  = blockIdx.z / HEADSN;

  const bf16*  A    = Conv + head * BWID;
  const bf16*  Bw   = (sel ? AGb : IGb) + (size_t)head * BWID * BWID;
  const float* bias = sel ? ag_b : ig_b;
  bf16*        Cp   = (sel ? Ga : Gx) + head * BWID;

  f32x4 acc[4][4] = {};
  const int srow = tid >> 3;
  const int spb  = (tid & 7) * 16;
  const int scb  = spb ^ ((srow & 7) << 4);

  const int lrow = lane & 15;
  const int swzc = (lane & 7) << 4;
  const int col0 = ((lane >> 4) * 16) ^ swzc;
  const int col1 = (64 + (lane >> 4) * 16) ^ swzc;
  const char* aBase = (const char*)As + (wy * 64 + lrow) * 128;
  const char* bBase = (const char*)Bs + (wx * 64 + lrow) * 128;

  for (int k0 = 0; k0 < BWID; k0 += 64) {
#pragma unroll
    for (int rd = 0; rd < 4; ++rd) {
      const int r = rd * 32 + srow;
      async_copy16(&As[rd * 2048 + wave * 512],
                   A + (size_t)(m0 + r) * LRUD + k0 + (scb >> 1));
      async_copy16(&Bs[rd * 2048 + wave * 512],
                   Bw + (size_t)(n0 + r) * BWID + k0 + (scb >> 1));
    }
    __syncthreads();
#pragma unroll
    for (int ks = 0; ks < 2; ++ks) {
      const int colk = ks ? col1 : col0;
      bf16x8 af[4], bfr[4];
#pragma unroll
      for (int f = 0; f < 4; ++f) {
        af[f]  = *(const bf16x8*)(aBase + f * 2048 + colk);
        bfr[f] = *(const bf16x8*)(bBase + f * 2048 + colk);
      }
#pragma unroll
      for (int fm = 0; fm < 4; ++fm)
#pragma unroll
        for (int fn = 0; fn < 4; ++fn)
          acc[fm][fn] = __builtin_amdgcn_mfma_f32_16x16x32_bf16(af[fm], bfr[fn], acc[fm][fn], 0, 0, 0);
    }
    __syncthreads();
  }

  const int mrb = (lane >> 4) * 4;
  const int ncc = lane & 15;
#pragma unroll
  for (int fm = 0; fm < 4; ++fm) {
#pragma unroll
    for (int fn = 0; fn < 4; ++fn) {
      const int n  = n0 + wx * 64 + fn * 16 + ncc;
      const float bv = bias[n];
#pragma unroll
      for (int r = 0; r < 4; ++r) {
        const int m = m0 + wy * 64 + fm * 16 + mrb + r;
        float v = acc[fm][fn][r] + bv;
        Cp[(size_t)m * LRUD + n] = __float2bfloat16(1.0f / (1.0f + expf(-v)));
      }
    }
  }
}

// ---------------------------------------------------------------------------
// single fused f32->bf16 conversion over all 6 buffers (compile-time ranges)
static constexpr int CV0 = NTOK * HID / 4;          // input
static constexpr int CVW = LRUD * HID / 4;          // each big weight
static constexpr int CVG = BWID * LRUD / 4;         // each gate weight
static constexpr int CVT_TOTAL = CV0 + 3 * CVW + 2 * CVG;

__device__ __forceinline__ void cvt4(const float* src, bf16* dst, int j) {
  const float4 v = *(const float4*)(src + (size_t)j * 4);
  dst[(size_t)j * 4 + 0] = __float2bfloat16(v.x);
  dst[(size_t)j * 4 + 1] = __float2bfloat16(v.y);
  dst[(size_t)j * 4 + 2] = __float2bfloat16(v.z);
  dst[(size_t)j * 4 + 3] = __float2bfloat16(v.w);
}

__global__ __launch_bounds__(256)
void cvt_all_kernel(const float* __restrict__ x_in, const float* __restrict__ w_y,
                    const float* __restrict__ w_x, const float* __restrict__ w_out,
                    const float* __restrict__ ig_w, const float* __restrict__ ag_w,
                    bf16* __restrict__ Xbf, bf16* __restrict__ Wyb,
                    bf16* __restrict__ Wxb, bf16* __restrict__ Wob,
                    bf16* __restrict__ IGb, bf16* __restrict__ AGb)
{
  int g = blockIdx.x * 256 + threadIdx.x;
  if (g < CV0)                       { cvt4(x_in,  Xbf, g); return; }
  g -= CV0;
  if (g < CVW)                       { cvt4(w_y,   Wyb, g); return; }
  g -= CVW;
  if (g < CVW)                       { cvt4(w_x,   Wxb, g); return; }
  g -= CVW;
  if (g < CVW)                       { cvt4(w_out, Wob, g); return; }
  g -= CVW;
  if (g < CVG)                       { cvt4(ig_w,  IGb, g); return; }
  g -= CVG;
  cvt4(ag_w, AGb, g);
}

// depthwise causal conv, width 4; 8 time-steps per thread (rolling window).
// R4-proven scalar form: 10240 blocks -> high TLP for this BW-bound kernel.
__global__ __launch_bounds__(256)
void conv_kernel(const bf16* __restrict__ Xb, const float* __restrict__ cw,
                 const float* __restrict__ cbias, bf16* __restrict__ out) {
  const int c  = blockIdx.x * 256 + threadIdx.x;
  const int t0 = blockIdx.y * 8;
  const int bb = blockIdx.z;
  size_t base = ((size_t)bb * SEQL + t0) * LRUD + c;
  const float w0 = cw[c * 4 + 0], w1 = cw[c * 4 + 1];
  const float w2 = cw[c * 4 + 2], w3 = cw[c * 4 + 3];
  const float bc = cbias[c];
  float xm1, xm2, xm3;
  if (blockIdx.y == 0) { xm1 = xm2 = xm3 = 0.f; }
  else {
    xm1 = __bfloat162float(Xb[base - (size_t)LRUD]);
    xm2 = __bfloat162float(Xb[base - (size_t)2 * LRUD]);
    xm3 = __bfloat162float(Xb[base - (size_t)3 * LRUD]);
  }
#pragma unroll
  for (int tl = 0; tl < 8; ++tl) {
    const float x = __bfloat162float(Xb[base]);
    out[base] = __float2bfloat16(bc + x * w3 + xm1 * w2 + xm2 * w1 + xm3 * w0);
    xm3 = xm2; xm2 = xm1; xm1 = x;
    base += LRUD;
  }
}

// recurrence inputs: a = exp(-8*ga*softplus(ap)); x = conv*gx*sqrt(1-a^2)
// IDENTICAL fp32 expressions in scan1 and scan3 (bitwise-consistent).
__device__ __forceinline__ void compute_ax(float conv, float gx, float ga, float sp,
                                           int t, float& a, float& x) {
  const float la  = -8.f * ga * sp;
  a               = expf(la);
  const float asq = expf(2.f * la);
  float mult      = sqrtf(fmaxf(1.f - asq, 0.f));
  if (t == 0) { a = 0.f; mult = 1.f; }
  x = conv * gx * mult;
}

// scan phase 1: per-chunk composition (R4 scalar form)
__global__ __launch_bounds__(256)
void scan1_kernel(const bf16* __restrict__ conv, const bf16* __restrict__ gxb,
                  const bf16* __restrict__ gab, const float* __restrict__ a_param,
                  float* __restrict__ cA, float* __restrict__ cX) {
  const int c     = blockIdx.x * 256 + threadIdx.x;
  const int chunk = blockIdx.y;
  const int b     = blockIdx.z;
  const float ap  = a_param[c];
  const float sp  = (ap > 20.f) ? ap : log1pf(expf(ap));
  size_t base = ((size_t)b * SEQL + (size_t)chunk * CHLEN) * LRUD + c;
  float A = 1.f, X = 0.f;
  for (int tl = 0; tl < CHLEN; ++tl) {
    float a, x;
    compute_ax(__bfloat162float(conv[base]), __bfloat162float(gxb[base]),
               __bfloat162float(gab[base]), sp, chunk * CHLEN + tl, a, x);
    X = a * X + x;
    A *= a;
    base += LRUD;
  }
  const size_t ci = ((size_t)b * NCHUNK + chunk) * LRUD + c;
  cA[ci] = A;
  cX[ci] = X;
}

// scan phase 2: sequential carry across chunks
__global__ __launch_bounds__(256)
void scan2_kernel(const float* __restrict__ cA, const float* __restrict__ cX,
                  const float* __restrict__ prev_h, float* __restrict__ pref) {
  const int g = blockIdx.x * 256 + threadIdx.x;
  const int b = g / LRUD;
  const int c = g % LRUD;
  float h = prev_h[g];
#pragma unroll 8
  for (int ch = 0; ch < NCHUNK; ++ch) {
    const size_t ci = ((size_t)b * NCHUNK + ch) * LRUD + c;
    pref[ci] = h;
    h = cA[ci] * h + cX[ci];
  }
}

// scan phase 3: replay with prefix, multiply by y_branch -> Hm (bf16).
// R4 scalar form. hm aliases conv (read-before-write per slot, per-thread).
__global__ __launch_bounds__(256)
void scan3_kernel(const bf16* __restrict__ conv, const bf16* __restrict__ gxb,
                  const bf16* __restrict__ gab, const float* __restrict__ a_param,
                  const float* __restrict__ pref, const bf16* __restrict__ yb,
                  bf16* __restrict__ hm) {
  const int c     = blockIdx.x * 256 + threadIdx.x;
  const int chunk = blockIdx.y;
  const int b     = blockIdx.z;
  const float ap  = a_param[c];
  const float sp  = (ap > 20.f) ? ap : log1pf(expf(ap));
  float h = pref[((size_t)b * NCHUNK + chunk) * LRUD + c];
  size_t base = ((size_t)b * SEQL + (size_t)chunk * CHLEN) * LRUD + c;
  for (int tl = 0; tl < CHLEN; ++tl) {
    float a, x;
    compute_ax(__bfloat162float(conv[base]), __bfloat162float(gxb[base]),
               __bfloat162float(gab[base]), sp, chunk * CHLEN + tl, a, x);
    h = a * h + x;
    hm[base] = __float2bfloat16(h * __bfloat162float(yb[base]));
    base += LRUD;
  }
}

// ---------------------------------------------------------------------------
extern "C" void kernel_launch(void* const* d_in, const int* in_sizes, int n_in,
                              void* d_out, int out_size, void* d_ws, size_t ws_size,
                              hipStream_t stream) {
  const float* x_in    = (const float*)d_in[0];
  // d_in[1] = position_ids: arange(S) per batch -> reset iff t==0; not read.
  const float* prev_h  = (const float*)d_in[2];
  const float* w_y     = (const float*)d_in[3];
  const float* b_y     = (const float*)d_in[4];
  const float* w_x     = (const float*)d_in[5];
  const float* b_x     = (const float*)d_in[6];
  const float* w_out   = (const float*)d_in[7];
  const float* b_out   = (const float*)d_in[8];
  const float* conv_w  = (const float*)d_in[9];
  const float* conv_b  = (const float*)d_in[10];
  const float* a_param = (const float*)d_in[11];
  const float* ig_w    = (const float*)d_in[12];
  const float* ig_b    = (const float*)d_in[13];
  const float* ag_w    = (const float*)d_in[14];
  const float* ag_b    = (const float*)d_in[15];

  char* ws = (char*)d_ws;
  size_t off = 0;
  auto alloc = [&](size_t bytes) -> char* {
    char* p = ws + off;
    off += (bytes + 255) & ~(size_t)255;
    return p;
  };
  bf16*  Xbf  = (bf16*)alloc((size_t)NTOK * HID * 2);     // input bf16; Gx alias later
  bf16*  Wyb  = (bf16*)alloc((size_t)LRUD * HID * 2);
  bf16*  Wxb  = (bf16*)alloc((size_t)LRUD * HID * 2);
  bf16*  Wob  = (bf16*)alloc((size_t)HID * LRUD * 2);
  bf16*  IGb  = (bf16*)alloc((size_t)BWID * LRUD * 2);
  bf16*  AGb  = (bf16*)alloc((size_t)BWID * LRUD * 2);
  bf16*  Conv = (bf16*)alloc((size_t)NTOK * LRUD * 2);    // conv out; Hm alias later
  float* cA   = (float*)alloc((size_t)BATCHN * NCHUNK * LRUD * 4);
  float* cX   = (float*)alloc((size_t)BATCHN * NCHUNK * LRUD * 4);
  float* pref = (float*)alloc((size_t)BATCHN * NCHUNK * LRUD * 4);

  // d_out doubles as scratch for two bf16 [NTOK][LRUD] buffers (dead before
  // the final GEMM fully overwrites d_out with fp32 output)
  bf16* Yb = (bf16*)d_out;
  bf16* Xb = (bf16*)d_out + (size_t)NTOK * LRUD;
  bf16* Gx = Xbf;   // input-gate sigmoid; Xbf dead after dual GEMM
  bf16* Ga = Xb;    // a-gate sigmoid;     Xb dead after conv
  bf16* Hm = Conv;  // h * y_branch;       scan3 reads conv[i] before writing hm[i]

  // one fused f32->bf16 conversion pass
  cvt_all_kernel<<<dim3(CVT_TOTAL / 256), 256, 0, stream>>>(
      x_in, w_y, w_x, w_out, ig_w, ag_w, Xbf, Wyb, Wxb, Wob, IGb, AGb);

  // GEMM1+GEMM2 merged on the R12 256^2 quadrant kernel (best dual: 249us):
  // z=0 -> Yb = gelu(X@w_y^T+b_y); z=1 -> Xb = X@w_x^T+b_x
  gemm256_kernel<1><<<dim3(LRUD / 256, NTOK / 256, 2), 512, 0, stream>>>(
      Xbf, HID, Wyb, Wxb, HID, b_y, b_x, Yb, Xb, LRUD, HID);
  // depthwise causal conv (R4 scalar form)
  conv_kernel<<<dim3(LRUD / 256, SEQL / 8, BATCHN), 256, 0, stream>>>(
      Xb, conv_w, conv_b, Conv);
  // both block-diagonal gates in one dispatch
  gate_gemm_kernel<<<dim3(BWID / 128, NTOK / 128, 2 * HEADSN), 256, 0, stream>>>(
      Conv, IGb, AGb, ig_b, ag_b, Gx, Ga);
  // chunked parallel linear-recurrence scan (R4 scalar forms)
  scan1_kernel<<<dim3(LRUD / 256, NCHUNK, BATCHN), 256, 0, stream>>>(
      Conv, Gx, Ga, a_param, cA, cX);
  scan2_kernel<<<dim3((BATCHN * LRUD) / 256), 256, 0, stream>>>(cA, cX, prev_h, pref);
  scan3_kernel<<<dim3(LRUD / 256, NCHUNK, BATCHN), 256, 0, stream>>>(
      Conv, Gx, Ga, a_param, pref, Yb, Hm);
  // GEMM3 on the R13 128^2-quadrant 2-block/CU kernel (best GEMM3: ~133us)
  gemm128q_kernel<0><<<dim3(HID / 128, NTOK / 128), 256, 0, stream>>>(
      Hm, LRUD, Wob, Wob, LRUD, b_out, b_out, (float*)d_out, (float*)d_out,
      HID, LRUD);

  (void)in_sizes; (void)n_in; (void)out_size; (void)ws_size;
}

// Round 15
// 554.237 us; speedup vs baseline: 1.0057x; 1.0057x over previous
//
#include <hip/hip_runtime.h>
#include <hip/hip_bf16.h>
#include <math.h>

typedef __hip_bfloat16 bf16;
typedef __attribute__((ext_vector_type(4))) float f32x4;
typedef __attribute__((ext_vector_type(8))) __bf16 bf16x8;

static constexpr int HID    = 2560;
static constexpr int LRUD   = 2560;
static constexpr int HEADSN = 10;
static constexpr int BWID   = 256;          // LRU / HEADS
static constexpr int SEQL   = 4096;
static constexpr int BATCHN = 2;
static constexpr int NTOK   = BATCHN * SEQL;   // 8192
static constexpr int NCHUNK = 128;             // scan chunks per sequence
static constexpr int CHLEN  = 32;              // NCHUNK*CHLEN == SEQL

#define GAS __attribute__((address_space(1)))
#define LAS __attribute__((address_space(3)))
#define MEMFENCE asm volatile("" ::: "memory")
#define PHASE_SYNC                                        \
  __builtin_amdgcn_s_barrier(); MEMFENCE;                 \
  asm volatile("s_waitcnt lgkmcnt(0)" ::: "memory");
#define PHASE_END                                         \
  __builtin_amdgcn_s_barrier(); MEMFENCE;
#define VMGATE6 asm volatile("s_waitcnt vmcnt(6)" ::: "memory")
#define VMGATE0 asm volatile("s_waitcnt vmcnt(0)" ::: "memory")
#define LGKM8   asm volatile("s_waitcnt lgkmcnt(8)" ::: "memory")

__device__ __forceinline__ void async_copy16(void* lds, const void* g) {
  __builtin_amdgcn_global_load_lds((const GAS unsigned int*)g,
                                   (LAS unsigned int*)lds, 16, 0, 0);
}

// ---------------------------------------------------------------------------
// R12-proven 256^2 quadrant 8-phase dual GEMM (measured 249us, MfmaUtil 37%).
// 8 waves (2M x 4N), per-wave 128x64: acc[8][4] (128 AGPR); a[4][2]+bl+bh
// (64 VGPR). Per phase: ONE C-quadrant x K=64 (16 MFMA) + ONE half-tile
// staged. Gate ledger / hazards as documented in R12.
// EPI 1: dual bf16 (z: 0=gelu->out0, 1=linear->out1).
// ---------------------------------------------------------------------------
template<int EPI>
__global__ __launch_bounds__(512, 2)
void gemm256_kernel(const bf16* __restrict__ A, int lda,
                    const bf16* __restrict__ B0p, const bf16* __restrict__ B1p,
                    int ldb,
                    const float* __restrict__ bias0, const float* __restrict__ bias1,
                    void* __restrict__ out0, void* __restrict__ out1,
                    int ldc, int K)
{
  __shared__ __align__(16) bf16 As[2][256 * 64];
  __shared__ __align__(16) bf16 Bs[2][256 * 64];

  const int tid  = threadIdx.x;
  const int wave = tid >> 6;
  const int lane = tid & 63;
  const int wm   = wave >> 2;     // 0..1
  const int wn   = wave & 3;      // 0..3

  // bijective XCD swizzle (nxy % 8 == 0)
  const int nxy  = gridDim.x * gridDim.y;
  const int orig = blockIdx.y * gridDim.x + blockIdx.x;
  const int swz  = (orig & 7) * (nxy >> 3) + (orig >> 3);
  const int m0   = (swz / gridDim.x) * 256;
  const int n0   = (swz % gridDim.x) * 256;

  const int zsel = (EPI == 1) ? (int)blockIdx.z : 0;
  const bf16*  Bw   = zsel ? B1p : B0p;
  const float* bias = zsel ? bias1 : bias0;

  const int NT = K / 64;
  f32x4  acc[8][4] = {};
  bf16x8 a[4][2], bl[2][2], bh[2][2];

  const int srow = tid >> 3;           // 0..63 within a chunk
  const int spb  = (tid & 7) * 16;     // physical byte col
  const int scb  = spb ^ ((srow & 7) << 4);   // stage source col (thread-const)

  // hoisted fragment addressing (row&7 == lane&7 for all frag rows)
  const int lrow = lane & 15;
  const int swzc = (lane & 7) << 4;
  const int col0 = ((lane >> 4) * 16) ^ swzc;         // ks=0
  const int col1 = (64 + (lane >> 4) * 16) ^ swzc;    // ks=1
  const char* aBase = (const char*)&As[0][0] + (wm * 128 + lrow) * 128;
  const char* bBase = (const char*)&Bs[0][0] + (wn * 64 + lrow) * 128;
  constexpr int BUFB = 256 * 64 * 2;   // bytes per LDS buffer

  auto stageA = [&](int t, int c) {    // chunk c: tile rows c*64..c*64+63
    const int r = c * 64 + srow;
    async_copy16(&As[t & 1][c * 4096 + wave * 512],
                 A + (size_t)(m0 + r) * lda + t * 64 + (scb >> 1));
  };
  auto stageB = [&](int t, int c) {
    const int r = c * 64 + srow;
    async_copy16(&Bs[t & 1][c * 4096 + wave * 512],
                 Bw + (size_t)(n0 + r) * ldb + t * 64 + (scb >> 1));
  };
  auto stA_lo = [&](int t) { stageA(t, 0); stageA(t, 2); };
  auto stA_hi = [&](int t) { stageA(t, 1); stageA(t, 3); };
  auto stB01  = [&](int t) { stageB(t, 0); stageB(t, 1); };
  auto stB23  = [&](int t) { stageB(t, 2); stageB(t, 3); };

  auto readAhalf = [&](int buf, int half) {    // 8 ds_read_b128 -> a[4][2]
    const char* p = aBase + buf * BUFB + half * 4 * 2048;
#pragma unroll
    for (int j = 0; j < 4; ++j) {
      a[j][0] = *(const bf16x8*)(p + j * 2048 + col0);
      a[j][1] = *(const bf16x8*)(p + j * 2048 + col1);
    }
  };
  auto readBlo = [&](int buf) {                // 4 reads -> bl[2][2] (fn 0,1)
    const char* p = bBase + buf * BUFB;
#pragma unroll
    for (int f = 0; f < 2; ++f) {
      bl[f][0] = *(const bf16x8*)(p + f * 2048 + col0);
      bl[f][1] = *(const bf16x8*)(p + f * 2048 + col1);
    }
  };
  auto readBhi = [&](int buf) {                // 4 reads -> bh[2][2] (fn 2,3)
    const char* p = bBase + buf * BUFB + 2 * 2048;
#pragma unroll
    for (int f = 0; f < 2; ++f) {
      bh[f][0] = *(const bf16x8*)(p + f * 2048 + col0);
      bh[f][1] = *(const bf16x8*)(p + f * 2048 + col1);
    }
  };
  auto mfmaQ = [&](int fmB, int fnB, bf16x8 (&bx)[2][2]) {  // 16 MFMA
#pragma unroll
    for (int ks = 0; ks < 2; ++ks)
#pragma unroll
      for (int fn = 0; fn < 2; ++fn)
#pragma unroll
        for (int fm = 0; fm < 4; ++fm)
          acc[fmB + fm][fnB + fn] = __builtin_amdgcn_mfma_f32_16x16x32_bf16(
              a[fm][ks], bx[fn][ks], acc[fmB + fm][fnB + fn], 0, 0, 0);
  };

  // prologue: t0 all 4 half-tiles + t1's {Alo,B01,B23} = 14 calls; drain t0
  stA_lo(0); stB01(0); stB23(0); stA_hi(0);
  stA_lo(1); stB01(1); stB23(1);
  VMGATE6;
  PHASE_END;

  const int NI = NT / 2;
  for (int i = 0; i < NI; ++i) {
    const int  t0 = 2 * i, t1 = 2 * i + 1;
    const bool s2 = (t0 + 2) < NT;       // == (t1+2)<NT since NT even

    // P1: Q1 on buf0
    readAhalf(0, 0); readBlo(0);
    stA_hi(t1);
    LGKM8;
    PHASE_SYNC;
    __builtin_amdgcn_s_setprio(1); mfmaQ(0, 0, bl); __builtin_amdgcn_s_setprio(0);
    PHASE_END;
    // P2: Q2
    readBhi(0);
    if (s2) stA_lo(t0 + 2);
    PHASE_SYNC;
    __builtin_amdgcn_s_setprio(1); mfmaQ(0, 2, bh); __builtin_amdgcn_s_setprio(0);
    PHASE_END;
    // P3: Q3 (a <- a-hi)
    readAhalf(0, 1);
    if (s2) stB01(t0 + 2);
    PHASE_SYNC;
    __builtin_amdgcn_s_setprio(1); mfmaQ(4, 2, bh); __builtin_amdgcn_s_setprio(0);
    PHASE_END;
    // P4: Q4 (reuse a-hi + bl); GATE: all of t1 landed
    if (s2) stB23(t0 + 2);
    PHASE_SYNC;
    __builtin_amdgcn_s_setprio(1); mfmaQ(4, 0, bl); __builtin_amdgcn_s_setprio(0);
    if (s2) { VMGATE6; } else { VMGATE0; }
    PHASE_END;
    // P5: Q1 on buf1
    readAhalf(1, 0); readBlo(1);
    if (s2) stA_hi(t0 + 2);
    LGKM8;
    PHASE_SYNC;
    __builtin_amdgcn_s_setprio(1); mfmaQ(0, 0, bl); __builtin_amdgcn_s_setprio(0);
    PHASE_END;
    // P6: Q2
    readBhi(1);
    if (s2) stA_lo(t1 + 2);
    PHASE_SYNC;
    __builtin_amdgcn_s_setprio(1); mfmaQ(0, 2, bh); __builtin_amdgcn_s_setprio(0);
    PHASE_END;
    // P7: Q3
    readAhalf(1, 1);
    if (s2) stB01(t1 + 2);
    PHASE_SYNC;
    __builtin_amdgcn_s_setprio(1); mfmaQ(4, 2, bh); __builtin_amdgcn_s_setprio(0);
    PHASE_END;
    // P8: Q4; GATE: all of t0+2 landed
    if (s2) stB23(t1 + 2);
    PHASE_SYNC;
    __builtin_amdgcn_s_setprio(1); mfmaQ(4, 0, bl); __builtin_amdgcn_s_setprio(0);
    if (s2) { VMGATE6; }
    PHASE_END;
  }

  // epilogue: C/D layout: col = lane&15, row = (lane>>4)*4 + reg
  const int mrb = (lane >> 4) * 4;
  const int ncc = lane & 15;
#pragma unroll
  for (int fm = 0; fm < 8; ++fm) {
#pragma unroll
    for (int fn = 0; fn < 4; ++fn) {
      const int n  = n0 + wn * 64 + fn * 16 + ncc;
      const float bv = bias[n];
#pragma unroll
      for (int r = 0; r < 4; ++r) {
        const int m = m0 + wm * 128 + fm * 16 + mrb + r;
        const size_t idx = (size_t)m * ldc + n;
        float v = acc[fm][fn][r] + bv;
        if constexpr (EPI == 0) {
          ((float*)out0)[idx] = v;
        } else {
          if (zsel == 0) {
            const float t = tanhf(0.7978845608028654f * (v + 0.044715f * v * v * v));
            ((bf16*)out0)[idx] = __float2bfloat16(0.5f * v * (1.0f + t));
          } else {
            ((bf16*)out1)[idx] = __float2bfloat16(v);
          }
        }
      }
    }
  }
}

// ---------------------------------------------------------------------------
// R13-proven 128^2-tile quadrant 8-phase GEMM at 2 BLOCKS/CU.
// 4 waves (2M x 2N), per-wave 64x64: acc[4][4] (64 AGPR), ~48 VGPR frags,
// 64KB LDS. Gate ledger as documented in R13 (verified for NT=4 tail too).
// EPI 0: fp32+bias (GEMM3). EPI 2: GATE mode — blockIdx.z encodes
// head = z%10, sel = z/10 (0: input gate B0p/bias0/out0; 1: a gate B1p/
// bias1/out1); per-head A/B/out offsets; sigmoid bf16 epilogue. Bias is
// per-within-head column (shape [256], broadcast across heads).
// ---------------------------------------------------------------------------
template<int EPI>
__global__ __launch_bounds__(256, 2)
void gemm128q_kernel(const bf16* __restrict__ A, int lda,
                     const bf16* __restrict__ B0p, const bf16* __restrict__ B1p,
                     int ldb,
                     const float* __restrict__ bias0, const float* __restrict__ bias1,
                     void* __restrict__ out0, void* __restrict__ out1,
                     int ldc, int K)
{
  __shared__ __align__(16) bf16 As[2][128 * 64];
  __shared__ __align__(16) bf16 Bs[2][128 * 64];

  const int tid  = threadIdx.x;
  const int wave = tid >> 6;      // 0..3
  const int lane = tid & 63;
  const int wm   = wave >> 1;     // 0..1
  const int wn   = wave & 1;      // 0..1

  // bijective XCD swizzle over (x,y) only (nxy % 8 == 0 for all our grids)
  const int nxy  = gridDim.x * gridDim.y;
  const int orig = blockIdx.y * gridDim.x + blockIdx.x;
  const int swz  = (orig & 7) * (nxy >> 3) + (orig >> 3);
  const int m0   = (swz / gridDim.x) * 128;
  const int n0   = (swz % gridDim.x) * 128;

  // pointer setup per mode
  const bf16*  Ap;
  const bf16*  Bw;
  const float* bias;
  bf16*        outg = nullptr;   // gate-mode output (head-offset applied)
  if constexpr (EPI == 2) {
    const int head = blockIdx.z % HEADSN;
    const int sel  = blockIdx.z / HEADSN;
    Ap   = A + head * BWID;
    Bw   = (sel ? B1p : B0p) + (size_t)head * BWID * BWID;
    bias = sel ? bias1 : bias0;
    outg = ((bf16*)(sel ? out1 : out0)) + head * BWID;
  } else {
    Ap   = A;
    Bw   = B0p;
    bias = bias0;
  }

  const int NT = K / 64;
  f32x4  acc[4][4] = {};
  bf16x8 a[2][2], bl[2][2], bh[2][2];

  const int srow = tid >> 3;           // 0..31 within a 32-row chunk
  const int spb  = (tid & 7) * 16;
  const int scb  = spb ^ ((srow & 7) << 4);   // inverse-swizzled source col

  // hoisted fragment addressing (frag row&7 == lane&7)
  const int lrow = lane & 15;
  const int swzc = (lane & 7) << 4;
  const int col0 = ((lane >> 4) * 16) ^ swzc;         // ks=0
  const int col1 = (64 + (lane >> 4) * 16) ^ swzc;    // ks=1
  const char* aBase = (const char*)&As[0][0] + (wm * 64 + lrow) * 128;
  const char* bBase = (const char*)&Bs[0][0] + (wn * 64 + lrow) * 128;
  constexpr int BUFB = 128 * 64 * 2;   // bytes per LDS buffer

  auto stageA = [&](int t, int c) {    // chunk c: tile rows c*32..c*32+31
    const int r = c * 32 + srow;
    async_copy16(&As[t & 1][c * 2048 + wave * 512],
                 Ap + (size_t)(m0 + r) * lda + t * 64 + (scb >> 1));
  };
  auto stageB = [&](int t, int c) {
    const int r = c * 32 + srow;
    async_copy16(&Bs[t & 1][c * 2048 + wave * 512],
                 Bw + (size_t)(n0 + r) * ldb + t * 64 + (scb >> 1));
  };
  auto stA_lo = [&](int t) { stageA(t, 0); stageA(t, 2); };
  auto stA_hi = [&](int t) { stageA(t, 1); stageA(t, 3); };
  auto stB_lo = [&](int t) { stageB(t, 0); stageB(t, 2); };
  auto stB_hi = [&](int t) { stageB(t, 1); stageB(t, 3); };

  auto readAhalf = [&](int buf, int half) {    // 4 ds_read_b128 -> a[2][2]
    const char* p = aBase + buf * BUFB + half * 2 * 2048;
#pragma unroll
    for (int j = 0; j < 2; ++j) {
      a[j][0] = *(const bf16x8*)(p + j * 2048 + col0);
      a[j][1] = *(const bf16x8*)(p + j * 2048 + col1);
    }
  };
  auto readBlo = [&](int buf) {                // 4 reads -> bl (fn 0,1)
    const char* p = bBase + buf * BUFB;
#pragma unroll
    for (int f = 0; f < 2; ++f) {
      bl[f][0] = *(const bf16x8*)(p + f * 2048 + col0);
      bl[f][1] = *(const bf16x8*)(p + f * 2048 + col1);
    }
  };
  auto readBhi = [&](int buf) {                // 4 reads -> bh (fn 2,3)
    const char* p = bBase + buf * BUFB + 2 * 2048;
#pragma unroll
    for (int f = 0; f < 2; ++f) {
      bh[f][0] = *(const bf16x8*)(p + f * 2048 + col0);
      bh[f][1] = *(const bf16x8*)(p + f * 2048 + col1);
    }
  };
  auto mfmaQ = [&](int fmB, int fnB, bf16x8 (&bx)[2][2]) {  // 8 MFMA
#pragma unroll
    for (int ks = 0; ks < 2; ++ks)
#pragma unroll
      for (int fn = 0; fn < 2; ++fn)
#pragma unroll
        for (int fm = 0; fm < 2; ++fm)
          acc[fmB + fm][fnB + fn] = __builtin_amdgcn_mfma_f32_16x16x32_bf16(
              a[fm][ks], bx[fn][ks], acc[fmB + fm][fnB + fn], 0, 0, 0);
  };

  // prologue: t0 all 4 halves + t1 {Alo,Blo,Bhi} = 14 calls; drain t0
  stA_lo(0); stB_lo(0); stB_hi(0); stA_hi(0);
  stA_lo(1); stB_lo(1); stB_hi(1);
  VMGATE6;
  PHASE_END;

  const int NI = NT / 2;
  for (int i = 0; i < NI; ++i) {
    const int  t0 = 2 * i, t1 = 2 * i + 1;
    const bool s2 = (t0 + 2) < NT;       // == (t1+2)<NT since NT even

    // P1
    readAhalf(0, 0); readBlo(0);
    stA_hi(t1);
    PHASE_SYNC;
    __builtin_amdgcn_s_setprio(1); mfmaQ(0, 0, bl); __builtin_amdgcn_s_setprio(0);
    PHASE_END;
    // P2
    readBhi(0);
    if (s2) stA_lo(t0 + 2);
    PHASE_SYNC;
    __builtin_amdgcn_s_setprio(1); mfmaQ(0, 2, bh); __builtin_amdgcn_s_setprio(0);
    PHASE_END;
    // P3
    readAhalf(0, 1);
    if (s2) stB_lo(t0 + 2);
    PHASE_SYNC;
    __builtin_amdgcn_s_setprio(1); mfmaQ(2, 2, bh); __builtin_amdgcn_s_setprio(0);
    PHASE_END;
    // P4 (gate: t1 fully landed)
    if (s2) stB_hi(t0 + 2);
    PHASE_SYNC;
    __builtin_amdgcn_s_setprio(1); mfmaQ(2, 0, bl); __builtin_amdgcn_s_setprio(0);
    if (s2) { VMGATE6; } else { VMGATE0; }
    PHASE_END;
    // P5
    readAhalf(1, 0); readBlo(1);
    if (s2) stA_hi(t0 + 2);
    PHASE_SYNC;
    __builtin_amdgcn_s_setprio(1); mfmaQ(0, 0, bl); __builtin_amdgcn_s_setprio(0);
    PHASE_END;
    // P6
    readBhi(1);
    if (s2) stA_lo(t1 + 2);
    PHASE_SYNC;
    __builtin_amdgcn_s_setprio(1); mfmaQ(0, 2, bh); __builtin_amdgcn_s_setprio(0);
    PHASE_END;
    // P7
    readAhalf(1, 1);
    if (s2) stB_lo(t1 + 2);
    PHASE_SYNC;
    __builtin_amdgcn_s_setprio(1); mfmaQ(2, 2, bh); __builtin_amdgcn_s_setprio(0);
    PHASE_END;
    // P8 (gate: t0+2 fully landed)
    if (s2) stB_hi(t1 + 2);
    PHASE_SYNC;
    __builtin_amdgcn_s_setprio(1); mfmaQ(2, 0, bl); __builtin_amdgcn_s_setprio(0);
    if (s2) { VMGATE6; }
    PHASE_END;
  }

  // epilogue: C/D layout: col = lane&15, row = (lane>>4)*4 + reg
  const int mrb = (lane >> 4) * 4;
  const int ncc = lane & 15;
#pragma unroll
  for (int fm = 0; fm < 4; ++fm) {
#pragma unroll
    for (int fn = 0; fn < 4; ++fn) {
      const int n  = n0 + wn * 64 + fn * 16 + ncc;
      const float bv = bias[n];
#pragma unroll
      for (int r = 0; r < 4; ++r) {
        const int m = m0 + wm * 64 + fm * 16 + mrb + r;
        float v = acc[fm][fn][r] + bv;
        if constexpr (EPI == 0) {
          ((float*)out0)[(size_t)m * ldc + n] = v;
        } else if constexpr (EPI == 2) {
          outg[(size_t)m * ldc + n] = __float2bfloat16(1.0f / (1.0f + expf(-v)));
        }
      }
    }
  }
}

// ---------------------------------------------------------------------------
// single fused f32->bf16 conversion over all 6 buffers (compile-time ranges)
static constexpr int CV0 = NTOK * HID / 4;          // input
static constexpr int CVW = LRUD * HID / 4;          // each big weight
static constexpr int CVG = BWID * LRUD / 4;         // each gate weight
static constexpr int CVT_TOTAL = CV0 + 3 * CVW + 2 * CVG;

__device__ __forceinline__ void cvt4(const float* src, bf16* dst, int j) {
  const float4 v = *(const float4*)(src + (size_t)j * 4);
  dst[(size_t)j * 4 + 0] = __float2bfloat16(v.x);
  dst[(size_t)j * 4 + 1] = __float2bfloat16(v.y);
  dst[(size_t)j * 4 + 2] = __float2bfloat16(v.z);
  dst[(size_t)j * 4 + 3] = __float2bfloat16(v.w);
}

__global__ __launch_bounds__(256)
void cvt_all_kernel(const float* __restrict__ x_in, const float* __restrict__ w_y,
                    const float* __restrict__ w_x, const float* __restrict__ w_out,
                    const float* __restrict__ ig_w, const float* __restrict__ ag_w,
                    bf16* __restrict__ Xbf, bf16* __restrict__ Wyb,
                    bf16* __restrict__ Wxb, bf16* __restrict__ Wob,
                    bf16* __restrict__ IGb, bf16* __restrict__ AGb)
{
  int g = blockIdx.x * 256 + threadIdx.x;
  if (g < CV0)                       { cvt4(x_in,  Xbf, g); return; }
  g -= CV0;
  if (g < CVW)                       { cvt4(w_y,   Wyb, g); return; }
  g -= CVW;
  if (g < CVW)                       { cvt4(w_x,   Wxb, g); return; }
  g -= CVW;
  if (g < CVW)                       { cvt4(w_out, Wob, g); return; }
  g -= CVW;
  if (g < CVG)                       { cvt4(ig_w,  IGb, g); return; }
  g -= CVG;
  cvt4(ag_w, AGb, g);
}

// depthwise causal conv, width 4; 8 time-steps per thread (rolling window).
// R4-proven scalar form: 10240 blocks -> high TLP for this BW-bound kernel.
__global__ __launch_bounds__(256)
void conv_kernel(const bf16* __restrict__ Xb, const float* __restrict__ cw,
                 const float* __restrict__ cbias, bf16* __restrict__ out) {
  const int c  = blockIdx.x * 256 + threadIdx.x;
  const int t0 = blockIdx.y * 8;
  const int bb = blockIdx.z;
  size_t base = ((size_t)bb * SEQL + t0) * LRUD + c;
  const float w0 = cw[c * 4 + 0], w1 = cw[c * 4 + 1];
  const float w2 = cw[c * 4 + 2], w3 = cw[c * 4 + 3];
  const float bc = cbias[c];
  float xm1, xm2, xm3;
  if (blockIdx.y == 0) { xm1 = xm2 = xm3 = 0.f; }
  else {
    xm1 = __bfloat162float(Xb[base - (size_t)LRUD]);
    xm2 = __bfloat162float(Xb[base - (size_t)2 * LRUD]);
    xm3 = __bfloat162float(Xb[base - (size_t)3 * LRUD]);
  }
#pragma unroll
  for (int tl = 0; tl < 8; ++tl) {
    const float x = __bfloat162float(Xb[base]);
    out[base] = __float2bfloat16(bc + x * w3 + xm1 * w2 + xm2 * w1 + xm3 * w0);
    xm3 = xm2; xm2 = xm1; xm1 = x;
    base += LRUD;
  }
}

// recurrence inputs: a = exp(-8*ga*softplus(ap)); x = conv*gx*sqrt(1-a^2)
// IDENTICAL fp32 expressions in scan1 and scan3 (bitwise-consistent).
__device__ __forceinline__ void compute_ax(float conv, float gx, float ga, float sp,
                                           int t, float& a, float& x) {
  const float la  = -8.f * ga * sp;
  a               = expf(la);
  const float asq = expf(2.f * la);
  float mult      = sqrtf(fmaxf(1.f - asq, 0.f));
  if (t == 0) { a = 0.f; mult = 1.f; }
  x = conv * gx * mult;
}

// scan phase 1: per-chunk composition (R4 scalar form)
__global__ __launch_bounds__(256)
void scan1_kernel(const bf16* __restrict__ conv, const bf16* __restrict__ gxb,
                  const bf16* __restrict__ gab, const float* __restrict__ a_param,
                  float* __restrict__ cA, float* __restrict__ cX) {
  const int c     = blockIdx.x * 256 + threadIdx.x;
  const int chunk = blockIdx.y;
  const int b     = blockIdx.z;
  const float ap  = a_param[c];
  const float sp  = (ap > 20.f) ? ap : log1pf(expf(ap));
  size_t base = ((size_t)b * SEQL + (size_t)chunk * CHLEN) * LRUD + c;
  float A = 1.f, X = 0.f;
  for (int tl = 0; tl < CHLEN; ++tl) {
    float a, x;
    compute_ax(__bfloat162float(conv[base]), __bfloat162float(gxb[base]),
               __bfloat162float(gab[base]), sp, chunk * CHLEN + tl, a, x);
    X = a * X + x;
    A *= a;
    base += LRUD;
  }
  const size_t ci = ((size_t)b * NCHUNK + chunk) * LRUD + c;
  cA[ci] = A;
  cX[ci] = X;
}

// scan phase 2: sequential carry across chunks
__global__ __launch_bounds__(256)
void scan2_kernel(const float* __restrict__ cA, const float* __restrict__ cX,
                  const float* __restrict__ prev_h, float* __restrict__ pref) {
  const int g = blockIdx.x * 256 + threadIdx.x;
  const int b = g / LRUD;
  const int c = g % LRUD;
  float h = prev_h[g];
#pragma unroll 8
  for (int ch = 0; ch < NCHUNK; ++ch) {
    const size_t ci = ((size_t)b * NCHUNK + ch) * LRUD + c;
    pref[ci] = h;
    h = cA[ci] * h + cX[ci];
  }
}

// scan phase 3: replay with prefix, multiply by y_branch -> Hm (bf16).
// R4 scalar form. hm aliases conv (read-before-write per slot, per-thread).
__global__ __launch_bounds__(256)
void scan3_kernel(const bf16* __restrict__ conv, const bf16* __restrict__ gxb,
                  const bf16* __restrict__ gab, const float* __restrict__ a_param,
                  const float* __restrict__ pref, const bf16* __restrict__ yb,
                  bf16* __restrict__ hm) {
  const int c     = blockIdx.x * 256 + threadIdx.x;
  const int chunk = blockIdx.y;
  const int b     = blockIdx.z;
  const float ap  = a_param[c];
  const float sp  = (ap > 20.f) ? ap : log1pf(expf(ap));
  float h = pref[((size_t)b * NCHUNK + chunk) * LRUD + c];
  size_t base = ((size_t)b * SEQL + (size_t)chunk * CHLEN) * LRUD + c;
  for (int tl = 0; tl < CHLEN; ++tl) {
    float a, x;
    compute_ax(__bfloat162float(conv[base]), __bfloat162float(gxb[base]),
               __bfloat162float(gab[base]), sp, chunk * CHLEN + tl, a, x);
    h = a * h + x;
    hm[base] = __float2bfloat16(h * __bfloat162float(yb[base]));
    base += LRUD;
  }
}

// ---------------------------------------------------------------------------
extern "C" void kernel_launch(void* const* d_in, const int* in_sizes, int n_in,
                              void* d_out, int out_size, void* d_ws, size_t ws_size,
                              hipStream_t stream) {
  const float* x_in    = (const float*)d_in[0];
  // d_in[1] = position_ids: arange(S) per batch -> reset iff t==0; not read.
  const float* prev_h  = (const float*)d_in[2];
  const float* w_y     = (const float*)d_in[3];
  const float* b_y     = (const float*)d_in[4];
  const float* w_x     = (const float*)d_in[5];
  const float* b_x     = (const float*)d_in[6];
  const float* w_out   = (const float*)d_in[7];
  const float* b_out   = (const float*)d_in[8];
  const float* conv_w  = (const float*)d_in[9];
  const float* conv_b  = (const float*)d_in[10];
  const float* a_param = (const float*)d_in[11];
  const float* ig_w    = (const float*)d_in[12];
  const float* ig_b    = (const float*)d_in[13];
  const float* ag_w    = (const float*)d_in[14];
  const float* ag_b    = (const float*)d_in[15];

  char* ws = (char*)d_ws;
  size_t off = 0;
  auto alloc = [&](size_t bytes) -> char* {
    char* p = ws + off;
    off += (bytes + 255) & ~(size_t)255;
    return p;
  };
  bf16*  Xbf  = (bf16*)alloc((size_t)NTOK * HID * 2);     // input bf16; Gx alias later
  bf16*  Wyb  = (bf16*)alloc((size_t)LRUD * HID * 2);
  bf16*  Wxb  = (bf16*)alloc((size_t)LRUD * HID * 2);
  bf16*  Wob  = (bf16*)alloc((size_t)HID * LRUD * 2);
  bf16*  IGb  = (bf16*)alloc((size_t)BWID * LRUD * 2);
  bf16*  AGb  = (bf16*)alloc((size_t)BWID * LRUD * 2);
  bf16*  Conv = (bf16*)alloc((size_t)NTOK * LRUD * 2);    // conv out; Hm alias later
  float* cA   = (float*)alloc((size_t)BATCHN * NCHUNK * LRUD * 4);
  float* cX   = (float*)alloc((size_t)BATCHN * NCHUNK * LRUD * 4);
  float* pref = (float*)alloc((size_t)BATCHN * NCHUNK * LRUD * 4);

  // d_out doubles as scratch for two bf16 [NTOK][LRUD] buffers (dead before
  // the final GEMM fully overwrites d_out with fp32 output)
  bf16* Yb = (bf16*)d_out;
  bf16* Xb = (bf16*)d_out + (size_t)NTOK * LRUD;
  bf16* Gx = Xbf;   // input-gate sigmoid; Xbf dead after dual GEMM
  bf16* Ga = Xb;    // a-gate sigmoid;     Xb dead after conv
  bf16* Hm = Conv;  // h * y_branch;       scan3 reads conv[i] before writing hm[i]

  // one fused f32->bf16 conversion pass
  cvt_all_kernel<<<dim3(CVT_TOTAL / 256), 256, 0, stream>>>(
      x_in, w_y, w_x, w_out, ig_w, ag_w, Xbf, Wyb, Wxb, Wob, IGb, AGb);

  // GEMM1+GEMM2 merged on the R12 256^2 quadrant kernel (best dual: 249us):
  // z=0 -> Yb = gelu(X@w_y^T+b_y); z=1 -> Xb = X@w_x^T+b_x
  gemm256_kernel<1><<<dim3(LRUD / 256, NTOK / 256, 2), 512, 0, stream>>>(
      Xbf, HID, Wyb, Wxb, HID, b_y, b_x, Yb, Xb, LRUD, HID);
  // depthwise causal conv (R4 scalar form)
  conv_kernel<<<dim3(LRUD / 256, SEQL / 8, BATCHN), 256, 0, stream>>>(
      Xb, conv_w, conv_b, Conv);
  // both block-diagonal gates on the 128q pipelined kernel (gate mode):
  // 2560 blocks at 2/CU = 5 exact rounds
  gemm128q_kernel<2><<<dim3(BWID / 128, NTOK / 128, 2 * HEADSN), 256, 0, stream>>>(
      Conv, LRUD, IGb, AGb, BWID, ig_b, ag_b, Gx, Ga, LRUD, BWID);
  // chunked parallel linear-recurrence scan (R4 scalar forms)
  scan1_kernel<<<dim3(LRUD / 256, NCHUNK, BATCHN), 256, 0, stream>>>(
      Conv, Gx, Ga, a_param, cA, cX);
  scan2_kernel<<<dim3((BATCHN * LRUD) / 256), 256, 0, stream>>>(cA, cX, prev_h, pref);
  scan3_kernel<<<dim3(LRUD / 256, NCHUNK, BATCHN), 256, 0, stream>>>(
      Conv, Gx, Ga, a_param, pref, Yb, Hm);
  // GEMM3 on the R13 128^2-quadrant 2-block/CU kernel (best GEMM3: ~133us)
  gemm128q_kernel<0><<<dim3(HID / 128, NTOK / 128), 256, 0, stream>>>(
      Hm, LRUD, Wob, Wob, LRUD, b_out, b_out, (float*)d_out, (float*)d_out,
      HID, LRUD);

  (void)in_sizes; (void)n_in; (void)out_size; (void)ws_size;
}